// Round 7
// baseline (198.554 us; speedup 1.0000x reference)
//
#include <hip/hip_runtime.h>
#include <math.h>

// Problem constants
#define NB   4
#define CCH  256
#define HH   64
#define WW   64
#define GG   8
#define GCH  32
#define PP   9
#define HIN  66
#define WIN  66
#define HWSZ 4096            // H*W
#define NPIX 16384           // N*H*W

// Workspace element counts (ushort unless noted)
#define X16_ELEMS (NPIX*CCH)            // 4194304
#define XP_ELEMS  (NB*HIN*WIN*CCH)      // 4460544
#define X1_ELEMS  (NPIX*CCH)            // 4194304
#define AGG_ELEMS (NPIX*CCH)            // 4194304
#define WIN16_ELEMS (CCH*CCH)           // 65536
#define WOUT16_ELEMS (CCH*CCH)          // 65536
#define WOM16_ELEMS (CCH*216)           // 55296
#define OFF_ELEMS (NPIX*144)            // float
#define MSK_ELEMS (NPIX*72)             // float

typedef __attribute__((ext_vector_type(8))) short bf16x8;
typedef __attribute__((ext_vector_type(4))) float f32x4;

__device__ __forceinline__ unsigned short f2bf(float f) {
    unsigned int u = __float_as_uint(f);
    unsigned int r = (u + 0x7FFFu + ((u >> 16) & 1u)) >> 16;
    return (unsigned short)r;
}
__device__ __forceinline__ float bf2f(unsigned short s) {
    return __uint_as_float(((unsigned int)s) << 16);
}

// LDS row stride (bf16 elems): 32 k + 8 pad = 80 B (16-B aligned rows)
#define AK 40

// ---------------------------------------------------------------------------
// Kernel 0: prep — x fp32->bf16, all weights ->bf16, zero xp pad ring
// blocks [0,2048): x16 ; [2048,2096): weights ; [2096,2356): ring
// ---------------------------------------------------------------------------
__global__ __launch_bounds__(256) void k_prep(
    const float* __restrict__ x, const float* __restrict__ w_in,
    const float* __restrict__ w_off, const float* __restrict__ w_mask,
    const float* __restrict__ w_out, unsigned short* __restrict__ x16,
    unsigned short* __restrict__ w_in16, unsigned short* __restrict__ wom16,
    unsigned short* __restrict__ w_out16, unsigned short* __restrict__ xp)
{
    const int b = blockIdx.x;
    const int tid = threadIdx.x;
    if (b < 2048) {
        size_t i0 = (size_t)b * 2048 + tid * 4;
#pragma unroll
        for (int h = 0; h < 2; h++) {
            float4 v = *(const float4*)&x[i0 + h * 1024];
            ushort4 o;
            o.x = f2bf(v.x); o.y = f2bf(v.y); o.z = f2bf(v.z); o.w = f2bf(v.w);
            *(ushort4*)&x16[i0 + h * 1024] = o;
        }
    } else if (b < 2096) {
        int gtid = (b - 2048) * 256 + tid;
        for (int i = gtid; i < 186368; i += 12288) {
            if (i < 65536) {
                w_in16[i] = f2bf(w_in[i]);
            } else if (i < 131072) {
                int j = i - 65536;
                w_out16[j] = f2bf(w_out[j]);
            } else {
                int j = i - 131072;           // < 55296
                int r = j / 216, c = j - r * 216;
                float v = (c < 144) ? w_off[r * 144 + c] : w_mask[r * 72 + c - 144];
                wom16[j] = f2bf(v);
            }
        }
    } else {
        int idx = (b - 2096) * 256 + tid;
        int seg = idx >> 6, ln = idx & 63;
        int n = seg / 260, rp = seg % 260;
        int h, w;
        if (rp < 66)       { h = 0;        w = rp; }
        else if (rp < 132) { h = 65;       w = rp - 66; }
        else if (rp < 196) { h = rp - 131; w = 0; }
        else               { h = rp - 195; w = 65; }
        uint2 z = make_uint2(0u, 0u);
        *(uint2*)&xp[(((size_t)n * HIN + h) * WIN + w) * CCH + ln * 4] = z;
    }
}

// ---------------------------------------------------------------------------
// Kernel 1: input projection  x16 @ w_in16 -> xp (padded ch-last bf16)
// 128(m) x 64(n) tile, BK=32; staging = pure ushort gathers + b64 LDS writes
// ---------------------------------------------------------------------------
__global__ __launch_bounds__(256) void k_gemm_in(
    const unsigned short* __restrict__ x16, const unsigned short* __restrict__ w16,
    const float* __restrict__ b_in, unsigned short* __restrict__ xp)
{
    __shared__ short As[128 * AK];
    __shared__ short Ws[64 * AK];

    const int m0  = blockIdx.x * 128;
    const int co0 = blockIdx.y * 64;
    const int tid = threadIdx.x;
    const int n   = m0 >> 12;
    const int hw0 = m0 & 4095;

    const int wave = tid >> 6;
    const int lane = tid & 63;
    const int r16  = lane & 15;
    const int quad = lane >> 4;
    const int mw   = wave * 32;

    const unsigned short* xa = x16 + (size_t)n * CCH * HWSZ + hw0;

    f32x4 acc[2][4];
#pragma unroll
    for (int i = 0; i < 2; i++)
#pragma unroll
        for (int j = 0; j < 4; j++) acc[i][j] = (f32x4){0.f, 0.f, 0.f, 0.f};

    for (int k0 = 0; k0 < CCH; k0 += 32) {
        // A: 128 m x 32 k; thread packs 4 k of one m -> b64
#pragma unroll
        for (int l = 0; l < 4; l++) {
            int idx = tid + l * 256;
            int m = idx & 127, kph = idx >> 7;   // kph 0..7
            unsigned int u0 = xa[(size_t)(k0 + 4 * kph + 0) * HWSZ + m];
            unsigned int u1 = xa[(size_t)(k0 + 4 * kph + 1) * HWSZ + m];
            unsigned int u2 = xa[(size_t)(k0 + 4 * kph + 2) * HWSZ + m];
            unsigned int u3 = xa[(size_t)(k0 + 4 * kph + 3) * HWSZ + m];
            uint2 pk = make_uint2(u0 | (u1 << 16), u2 | (u3 << 16));
            *(uint2*)&As[m * AK + kph * 4] = pk;
        }
        // W: 32 k x 64 n
#pragma unroll
        for (int l = 0; l < 2; l++) {
            int idx = tid + l * 256;
            int nn = idx & 63, kph = idx >> 6;   // kph 0..7
            unsigned int u0 = w16[(size_t)(k0 + 4 * kph + 0) * CCH + co0 + nn];
            unsigned int u1 = w16[(size_t)(k0 + 4 * kph + 1) * CCH + co0 + nn];
            unsigned int u2 = w16[(size_t)(k0 + 4 * kph + 2) * CCH + co0 + nn];
            unsigned int u3 = w16[(size_t)(k0 + 4 * kph + 3) * CCH + co0 + nn];
            uint2 pk = make_uint2(u0 | (u1 << 16), u2 | (u3 << 16));
            *(uint2*)&Ws[nn * AK + kph * 4] = pk;
        }
        __syncthreads();

        bf16x8 a0 = *(const bf16x8*)&As[(mw + r16) * AK + quad * 8];
        bf16x8 a1 = *(const bf16x8*)&As[(mw + 16 + r16) * AK + quad * 8];
#pragma unroll
        for (int nt = 0; nt < 4; nt++) {
            bf16x8 bfr = *(const bf16x8*)&Ws[(nt * 16 + r16) * AK + quad * 8];
            acc[0][nt] = __builtin_amdgcn_mfma_f32_16x16x32_bf16(a0, bfr, acc[0][nt], 0, 0, 0);
            acc[1][nt] = __builtin_amdgcn_mfma_f32_16x16x32_bf16(a1, bfr, acc[1][nt], 0, 0, 0);
        }
        __syncthreads();
    }

#pragma unroll
    for (int nt = 0; nt < 4; nt++) {
        int co = co0 + nt * 16 + r16;
        float bias = b_in[co];
#pragma unroll
        for (int mt = 0; mt < 2; mt++) {
            int mbase = mw + mt * 16 + quad * 4;
#pragma unroll
            for (int r = 0; r < 4; r++) {
                int hw = hw0 + mbase + r;
                int h = hw >> 6, w = hw & 63;
                xp[(((size_t)n * HIN + (h + 1)) * WIN + (w + 1)) * CCH + co] =
                    f2bf(acc[mt][nt][r] + bias);
            }
        }
    }
}

// ---------------------------------------------------------------------------
// Kernel 2: depthwise 3x3 + bias + LayerNorm(C) + exact GELU -> x1 (bf16)
// reads x16 (bf16); one block per (n,h), 512 thr; w+-1 via shuffles
// ---------------------------------------------------------------------------
#define SDW_STRIDE 258
__global__ __launch_bounds__(512) void k_dw_ln_gelu(
    const unsigned short* __restrict__ x16, const float* __restrict__ w_dw,
    const float* __restrict__ b_dw, const float* __restrict__ ln_g,
    const float* __restrict__ ln_b, unsigned short* __restrict__ x1)
{
    __shared__ unsigned short sdw[64 * SDW_STRIDE];   // [w][c] bf16
    __shared__ float r1s[8][64];
    __shared__ float r2s[8][64];
    __shared__ float mu_s[64];
    __shared__ float rs_s[64];

    const int h = blockIdx.x;
    const int n = blockIdx.y;
    const int tid = threadIdx.x;
    const int wave = tid >> 6;
    const int lane = tid & 63;        // = w in phase 1

    const unsigned short* xn = x16 + (size_t)n * CCH * HWSZ;
    const bool h0ok = (h > 0);
    const bool h2ok = (h < HH - 1);

    float s1 = 0.f, s2 = 0.f;

#pragma unroll 4
    for (int it = 0; it < 32; it++) {
        const int c = it * 8 + wave;
        const unsigned short* xc = xn + (size_t)c * HWSZ + h * WW + lane;
        float v0 = h0ok ? bf2f(xc[-WW]) : 0.f;
        float v1 = bf2f(xc[0]);
        float v2 = h2ok ? bf2f(xc[WW]) : 0.f;

        const float* wk = w_dw + c * 9;
        float acc = b_dw[c];

        float l0 = __shfl_up(v0, 1);  if (lane == 0)  l0 = 0.f;
        float r0 = __shfl_down(v0, 1); if (lane == 63) r0 = 0.f;
        acc += wk[0] * l0 + wk[1] * v0 + wk[2] * r0;

        float l1 = __shfl_up(v1, 1);  if (lane == 0)  l1 = 0.f;
        float r1 = __shfl_down(v1, 1); if (lane == 63) r1 = 0.f;
        acc += wk[3] * l1 + wk[4] * v1 + wk[5] * r1;

        float l2 = __shfl_up(v2, 1);  if (lane == 0)  l2 = 0.f;
        float r2 = __shfl_down(v2, 1); if (lane == 63) r2 = 0.f;
        acc += wk[6] * l2 + wk[7] * v2 + wk[8] * r2;

        s1 += acc;
        s2 += acc * acc;
        sdw[lane * SDW_STRIDE + c] = f2bf(acc);
    }

    r1s[wave][lane] = s1;
    r2s[wave][lane] = s2;
    __syncthreads();

    if (tid < 64) {
        float a1 = 0.f, a2 = 0.f;
#pragma unroll
        for (int q = 0; q < 8; q++) { a1 += r1s[q][tid]; a2 += r2s[q][tid]; }
        float mu = a1 * (1.0f / 256.0f);
        float var = a2 * (1.0f / 256.0f) - mu * mu;
        mu_s[tid] = mu;
        rs_s[tid] = rsqrtf(var + 1e-5f);
    }
    __syncthreads();

    const int c0 = (tid & 63) * 4;
    const int wq = tid >> 6;          // 0..7
    float g4[4], b4[4];
#pragma unroll
    for (int i = 0; i < 4; i++) { g4[i] = ln_g[c0 + i]; b4[i] = ln_b[c0 + i]; }

    unsigned short* x1p = x1 + (((size_t)n * HH + h) * WW) * CCH + c0;
#pragma unroll
    for (int pass = 0; pass < 8; pass++) {
        int w = wq + pass * 8;
        float mu = mu_s[w], rs = rs_s[w];
        const unsigned short* row = &sdw[w * SDW_STRIDE + c0];
        unsigned short tmp[4];
#pragma unroll
        for (int i = 0; i < 4; i++) {
            float v = (bf2f(row[i]) - mu) * rs * g4[i] + b4[i];
            tmp[i] = f2bf(0.5f * v * (1.0f + erff(v * 0.70710678118654752f)));
        }
        ushort4 o; o.x = tmp[0]; o.y = tmp[1]; o.z = tmp[2]; o.w = tmp[3];
        *(ushort4*)&x1p[(size_t)w * CCH] = o;
    }
}

// ---------------------------------------------------------------------------
// Kernel 3: x1(bf16) @ wom16 + bias -> off, msk (fp32)
// ---------------------------------------------------------------------------
__global__ __launch_bounds__(256) void k_gemm_offmask(
    const unsigned short* __restrict__ x1, const unsigned short* __restrict__ wom16,
    const float* __restrict__ b_off, const float* __restrict__ b_mask,
    float* __restrict__ off, float* __restrict__ msk)
{
    __shared__ short As[128 * AK];
    __shared__ short Ws[64 * AK];

    const int m0  = blockIdx.x * 128;
    const int co0 = blockIdx.y * 64;       // cols 0..215 valid
    const int tid = threadIdx.x;

    const int wave = tid >> 6;
    const int lane = tid & 63;
    const int r16  = lane & 15;
    const int quad = lane >> 4;
    const int mw   = wave * 32;

    f32x4 acc[2][4];
#pragma unroll
    for (int i = 0; i < 2; i++)
#pragma unroll
        for (int j = 0; j < 4; j++) acc[i][j] = (f32x4){0.f, 0.f, 0.f, 0.f};

    for (int k0 = 0; k0 < CCH; k0 += 32) {
        // A copy: uint4 (8 bf16) -> b128
#pragma unroll
        for (int l = 0; l < 2; l++) {
            int idx = tid + l * 256;
            int m = idx >> 2, kq = idx & 3;
            uint4 v = *(const uint4*)&x1[(size_t)(m0 + m) * CCH + k0 + kq * 8];
            *(uint4*)&As[m * AK + kq * 8] = v;
        }
        // W: guarded gather from wom16 (stride 216), b64 packs
#pragma unroll
        for (int l = 0; l < 2; l++) {
            int idx = tid + l * 256;
            int nn = idx & 63, kph = idx >> 6;
            int col = co0 + nn;
            unsigned int u0 = 0, u1 = 0, u2 = 0, u3 = 0;
            if (col < 216) {
                u0 = wom16[(size_t)(k0 + 4 * kph + 0) * 216 + col];
                u1 = wom16[(size_t)(k0 + 4 * kph + 1) * 216 + col];
                u2 = wom16[(size_t)(k0 + 4 * kph + 2) * 216 + col];
                u3 = wom16[(size_t)(k0 + 4 * kph + 3) * 216 + col];
            }
            uint2 pk = make_uint2(u0 | (u1 << 16), u2 | (u3 << 16));
            *(uint2*)&Ws[nn * AK + kph * 4] = pk;
        }
        __syncthreads();

        bf16x8 a0 = *(const bf16x8*)&As[(mw + r16) * AK + quad * 8];
        bf16x8 a1 = *(const bf16x8*)&As[(mw + 16 + r16) * AK + quad * 8];
#pragma unroll
        for (int nt = 0; nt < 4; nt++) {
            bf16x8 bfr = *(const bf16x8*)&Ws[(nt * 16 + r16) * AK + quad * 8];
            acc[0][nt] = __builtin_amdgcn_mfma_f32_16x16x32_bf16(a0, bfr, acc[0][nt], 0, 0, 0);
            acc[1][nt] = __builtin_amdgcn_mfma_f32_16x16x32_bf16(a1, bfr, acc[1][nt], 0, 0, 0);
        }
        __syncthreads();
    }

#pragma unroll
    for (int nt = 0; nt < 4; nt++) {
        int col = co0 + nt * 16 + r16;
        if (col >= 216) continue;
        float bias = (col < 144) ? b_off[col] : b_mask[col - 144];
#pragma unroll
        for (int mt = 0; mt < 2; mt++) {
            int mbase = m0 + mw + mt * 16 + quad * 4;
#pragma unroll
            for (int r = 0; r < 4; r++) {
                int p = mbase + r;
                float v = acc[mt][nt][r] + bias;
                if (col < 144) off[(size_t)p * 144 + col] = v;
                else           msk[(size_t)p * 72 + col - 144] = v;
            }
        }
    }
}

// ---------------------------------------------------------------------------
// Kernel 4: deformable sampling + aggregation, 8 px/block, 8 ch/lane (uint4)
// ---------------------------------------------------------------------------
__device__ __forceinline__ void acc8_tap(float* a, uint4 vv, float wgt) {
    a[0] += wgt * __uint_as_float(vv.x << 16);
    a[1] += wgt * __uint_as_float(vv.x & 0xffff0000u);
    a[2] += wgt * __uint_as_float(vv.y << 16);
    a[3] += wgt * __uint_as_float(vv.y & 0xffff0000u);
    a[4] += wgt * __uint_as_float(vv.z << 16);
    a[5] += wgt * __uint_as_float(vv.z & 0xffff0000u);
    a[6] += wgt * __uint_as_float(vv.w << 16);
    a[7] += wgt * __uint_as_float(vv.w & 0xffff0000u);
}

__global__ __launch_bounds__(256) void k_sample_agg(
    const unsigned short* __restrict__ xp, const float* __restrict__ off,
    const float* __restrict__ msk, unsigned short* __restrict__ agg)
{
    __shared__ float  sm[576];
    __shared__ int2   tco[576];
    __shared__ float4 twt[576];

    const int tid = threadIdx.x;
    const int s0 = blockIdx.x * 8;

    if (tid < 64) {
        const int pix = tid >> 3, g = tid & 7;
        const float* mskp = msk + (size_t)(s0 + pix) * 72 + g * 9;
        float e[9];
        float mx = -1e30f;
#pragma unroll
        for (int p = 0; p < PP; p++) { e[p] = mskp[p]; mx = fmaxf(mx, e[p]); }
        float sum = 0.f;
#pragma unroll
        for (int p = 0; p < PP; p++) { e[p] = __expf(e[p] - mx); sum += e[p]; }
        float rs = 1.0f / sum;
#pragma unroll
        for (int p = 0; p < PP; p++) sm[tid * 9 + p] = e[p] * rs;
    }
    __syncthreads();

    for (int idx = tid; idx < 576; idx += 256) {
        int pix = idx / 72;
        int rem = idx - pix * 72;
        int g = rem / 9;
        int p = rem - g * 9;
        int s = s0 + pix;
        int hw = s & 4095;
        int h = hw >> 6, w = hw & 63;
        const float* offp = off + (size_t)s * 144 + g * 18 + p * 2;
        float ox = offp[0], oy = offp[1];
        int i = p / 3, j = p - i * 3;
        float fx = (float)(w + i) + ox;
        float fy = (float)(h + j) + oy;
        float x0f = floorf(fx), y0f = floorf(fy);
        int x0 = (int)x0f, y0 = (int)y0f;
        float wx = fx - x0f, wy = fy - y0f;
        float m = sm[idx];
        float w00 = (1.f - wx) * (1.f - wy) * m;
        float w10 = wx * (1.f - wy) * m;
        float w01 = (1.f - wx) * wy * m;
        float w11 = wx * wy * m;
        int x1c = x0 + 1, y1c = y0 + 1;
        if (!((x0  >= 0) && (x0  < WIN))) { w00 = 0.f; w01 = 0.f; }
        if (!((x1c >= 0) && (x1c < WIN))) { w10 = 0.f; w11 = 0.f; }
        if (!((y0  >= 0) && (y0  < HIN))) { w00 = 0.f; w10 = 0.f; }
        if (!((y1c >= 0) && (y1c < HIN))) { w01 = 0.f; w11 = 0.f; }
        int cx0 = min(max(x0, 0), WIN - 1), cx1 = min(max(x1c, 0), WIN - 1);
        int cy0 = min(max(y0, 0), HIN - 1), cy1 = min(max(y1c, 0), HIN - 1);
        tco[idx] = make_int2(cx0 | (cx1 << 16), cy0 | (cy1 << 16));
        twt[idx] = make_float4(w00, w10, w01, w11);
    }
    __syncthreads();

    // Phase C: pix = tid>>5; lane5 = tid&31; g = lane5>>2; c8 = lane5&3
    const int pix = tid >> 5;
    const int l5 = tid & 31;
    const int g = l5 >> 2, c8 = l5 & 3;
    const int s = s0 + pix;
    const int n = s >> 12;
    const unsigned short* base = xp + (size_t)n * HIN * WIN * CCH + g * GCH + c8 * 8;
    const int tbase = pix * 72 + g * 9;

    float a[8];
#pragma unroll
    for (int i = 0; i < 8; i++) a[i] = 0.f;

#pragma unroll
    for (int p = 0; p < PP; p++) {
        int2 cc = tco[tbase + p];
        float4 wt = twt[tbase + p];
        int cx0 = cc.x & 0xFFFF, cx1 = cc.x >> 16;
        int cy0 = cc.y & 0xFFFF, cy1 = cc.y >> 16;
        const unsigned short* r0 = base + (size_t)(cy0 * WIN) * CCH;
        const unsigned short* r1 = base + (size_t)(cy1 * WIN) * CCH;
        uint4 v00 = *(const uint4*)&r0[(size_t)cx0 * CCH];
        uint4 v10 = *(const uint4*)&r0[(size_t)cx1 * CCH];
        uint4 v01 = *(const uint4*)&r1[(size_t)cx0 * CCH];
        uint4 v11 = *(const uint4*)&r1[(size_t)cx1 * CCH];
        acc8_tap(a, v00, wt.x);
        acc8_tap(a, v10, wt.y);
        acc8_tap(a, v01, wt.z);
        acc8_tap(a, v11, wt.w);
    }

    uint4 o;
    o.x = (unsigned int)f2bf(a[0]) | ((unsigned int)f2bf(a[1]) << 16);
    o.y = (unsigned int)f2bf(a[2]) | ((unsigned int)f2bf(a[3]) << 16);
    o.z = (unsigned int)f2bf(a[4]) | ((unsigned int)f2bf(a[5]) << 16);
    o.w = (unsigned int)f2bf(a[6]) | ((unsigned int)f2bf(a[7]) << 16);
    *(uint4*)&agg[(size_t)s * CCH + g * GCH + c8 * 8] = o;
}

// ---------------------------------------------------------------------------
// Kernel 5: agg(bf16) @ w_out16 + b_out -> BN -> SiLU -> out (NCHW fp32)
// ---------------------------------------------------------------------------
__global__ __launch_bounds__(256) void k_gemm_out(
    const unsigned short* __restrict__ agg, const unsigned short* __restrict__ w16,
    const float* __restrict__ b_out, const float* __restrict__ bn_g,
    const float* __restrict__ bn_b, const float* __restrict__ bn_mean,
    const float* __restrict__ bn_var, float* __restrict__ out)
{
    __shared__ short As[128 * AK];
    __shared__ short Ws[64 * AK];

    const int m0  = blockIdx.x * 128;
    const int co0 = blockIdx.y * 64;
    const int tid = threadIdx.x;
    const int n   = m0 >> 12;
    const int hw0 = m0 & 4095;

    const int wave = tid >> 6;
    const int lane = tid & 63;
    const int r16  = lane & 15;
    const int quad = lane >> 4;
    const int mw   = wave * 32;

    f32x4 acc[2][4];
#pragma unroll
    for (int i = 0; i < 2; i++)
#pragma unroll
        for (int j = 0; j < 4; j++) acc[i][j] = (f32x4){0.f, 0.f, 0.f, 0.f};

    for (int k0 = 0; k0 < CCH; k0 += 32) {
#pragma unroll
        for (int l = 0; l < 2; l++) {
            int idx = tid + l * 256;
            int m = idx >> 2, kq = idx & 3;
            uint4 v = *(const uint4*)&agg[(size_t)(m0 + m) * CCH + k0 + kq * 8];
            *(uint4*)&As[m * AK + kq * 8] = v;
        }
#pragma unroll
        for (int l = 0; l < 2; l++) {
            int idx = tid + l * 256;
            int nn = idx & 63, kph = idx >> 6;
            unsigned int u0 = w16[(size_t)(k0 + 4 * kph + 0) * CCH + co0 + nn];
            unsigned int u1 = w16[(size_t)(k0 + 4 * kph + 1) * CCH + co0 + nn];
            unsigned int u2 = w16[(size_t)(k0 + 4 * kph + 2) * CCH + co0 + nn];
            unsigned int u3 = w16[(size_t)(k0 + 4 * kph + 3) * CCH + co0 + nn];
            uint2 pk = make_uint2(u0 | (u1 << 16), u2 | (u3 << 16));
            *(uint2*)&Ws[nn * AK + kph * 4] = pk;
        }
        __syncthreads();

        bf16x8 a0 = *(const bf16x8*)&As[(mw + r16) * AK + quad * 8];
        bf16x8 a1 = *(const bf16x8*)&As[(mw + 16 + r16) * AK + quad * 8];
#pragma unroll
        for (int nt = 0; nt < 4; nt++) {
            bf16x8 bfr = *(const bf16x8*)&Ws[(nt * 16 + r16) * AK + quad * 8];
            acc[0][nt] = __builtin_amdgcn_mfma_f32_16x16x32_bf16(a0, bfr, acc[0][nt], 0, 0, 0);
            acc[1][nt] = __builtin_amdgcn_mfma_f32_16x16x32_bf16(a1, bfr, acc[1][nt], 0, 0, 0);
        }
        __syncthreads();
    }

#pragma unroll
    for (int nt = 0; nt < 4; nt++) {
        int co = co0 + nt * 16 + r16;
        float mean = bn_mean[co];
        float rstd = rsqrtf(bn_var[co] + 1e-5f);
        float gg = bn_g[co], bb = bn_b[co], bo = b_out[co];
#pragma unroll
        for (int mt = 0; mt < 2; mt++) {
            int hwb = hw0 + mw + mt * 16 + quad * 4;
            float tmp[4];
#pragma unroll
            for (int r = 0; r < 4; r++) {
                float y = acc[mt][nt][r] + bo;
                float yh = (y - mean) * rstd * gg + bb;
                tmp[r] = yh / (1.0f + __expf(-yh));
            }
            float4 v = make_float4(tmp[0], tmp[1], tmp[2], tmp[3]);
            *(float4*)&out[((size_t)n * CCH + co) * HWSZ + hwb] = v;
        }
    }
}

// ---------------------------------------------------------------------------
extern "C" void kernel_launch(void* const* d_in, const int* in_sizes, int n_in,
                              void* d_out, int out_size, void* d_ws, size_t ws_size,
                              hipStream_t stream)
{
    const float* x       = (const float*)d_in[0];
    const float* w_in    = (const float*)d_in[1];
    const float* b_in    = (const float*)d_in[2];
    const float* w_dw    = (const float*)d_in[3];
    const float* b_dw    = (const float*)d_in[4];
    const float* ln_g    = (const float*)d_in[5];
    const float* ln_b    = (const float*)d_in[6];
    const float* w_off   = (const float*)d_in[7];
    const float* b_off   = (const float*)d_in[8];
    const float* w_mask  = (const float*)d_in[9];
    const float* b_mask  = (const float*)d_in[10];
    const float* w_out   = (const float*)d_in[11];
    const float* b_out   = (const float*)d_in[12];
    const float* bn_g    = (const float*)d_in[13];
    const float* bn_b    = (const float*)d_in[14];
    const float* bn_mean = (const float*)d_in[15];
    const float* bn_var  = (const float*)d_in[16];
    float* out = (float*)d_out;

    unsigned short* x16    = (unsigned short*)d_ws;
    unsigned short* xp     = x16 + X16_ELEMS;
    unsigned short* x1     = xp + XP_ELEMS;
    unsigned short* agg    = x1 + X1_ELEMS;
    unsigned short* w_in16 = agg + AGG_ELEMS;
    unsigned short* w_out16= w_in16 + WIN16_ELEMS;
    unsigned short* wom16  = w_out16 + WOUT16_ELEMS;
    float* off = (float*)(wom16 + WOM16_ELEMS);
    float* msk = off + OFF_ELEMS;
    // total ~48.6 MB

    k_prep<<<dim3(2356), 256, 0, stream>>>(x, w_in, w_off, w_mask, w_out,
                                           x16, w_in16, wom16, w_out16, xp);
    k_gemm_in<<<dim3(128, 4), 256, 0, stream>>>(x16, w_in16, b_in, xp);
    k_dw_ln_gelu<<<dim3(64, 4), 512, 0, stream>>>(x16, w_dw, b_dw, ln_g, ln_b, x1);
    k_gemm_offmask<<<dim3(128, 4), 256, 0, stream>>>(x1, wom16, b_off, b_mask, off, msk);
    k_sample_agg<<<dim3(2048), 256, 0, stream>>>(xp, off, msk, agg);
    k_gemm_out<<<dim3(128, 4), 256, 0, stream>>>(agg, w_out16, b_out, bn_g, bn_b, bn_mean, bn_var, out);
}

// Round 8
// 181.409 us; speedup vs baseline: 1.0945x; 1.0945x over previous
//
#include <hip/hip_runtime.h>
#include <math.h>

// Problem constants
#define NB   4
#define CCH  256
#define HH   64
#define WW   64
#define GG   8
#define GCH  32
#define PP   9
#define HIN  66
#define WIN  66
#define HWSZ 4096            // H*W
#define NPIX 16384           // N*H*W

// Workspace element counts
#define XP_ELEMS  (NB*HIN*WIN*CCH)      // 4460544  (ushort/bf16)
#define X1_ELEMS  (NPIX*CCH)            // 4194304  (ushort/bf16)
#define AGG_ELEMS (NPIX*CCH)            // 4194304  (ushort/bf16)
#define OFF_ELEMS (NPIX*144)            // float
#define MSK_ELEMS (NPIX*72)             // float

typedef __attribute__((ext_vector_type(8))) short bf16x8;
typedef __attribute__((ext_vector_type(4))) float f32x4;

__device__ __forceinline__ unsigned short f2bf(float f) {
    unsigned int u = __float_as_uint(f);
    unsigned int r = (u + 0x7FFFu + ((u >> 16) & 1u)) >> 16;
    return (unsigned short)r;
}
__device__ __forceinline__ float bf2f(unsigned short s) {
    return __uint_as_float(((unsigned int)s) << 16);
}
__device__ __forceinline__ unsigned int f2bf_pk(float lo, float hi) {
    return (unsigned int)f2bf(lo) | ((unsigned int)f2bf(hi) << 16);
}

// LDS row stride (bf16 elems): 32 k + 8 pad = 80 B (16-B aligned rows)
#define AK 40

// ---------------------------------------------------------------------------
// Kernel 0: zero only the pad ring of xp (bf16)
// ---------------------------------------------------------------------------
__global__ __launch_bounds__(64) void k_zero_ring(unsigned short* __restrict__ xp)
{
    int b = blockIdx.x;
    int n = b / 260;
    int rp = b % 260;
    int h, w;
    if (rp < 66)       { h = 0;        w = rp; }
    else if (rp < 132) { h = 65;       w = rp - 66; }
    else if (rp < 196) { h = rp - 131; w = 0; }    // h = 1..64
    else               { h = rp - 195; w = 65; }   // h = 1..64
    uint2 z = make_uint2(0u, 0u);
    *(uint2*)&xp[(((size_t)n * HIN + h) * WIN + w) * CCH + threadIdx.x * 4] = z;
}

// ---------------------------------------------------------------------------
// Kernel 1: input projection  x(NCHW fp32) @ w_in -> xp (padded ch-last bf16)
// 128(m) x 64(n) tile, BK=32, register-prefetch double buffer
// ---------------------------------------------------------------------------
__global__ __launch_bounds__(256) void k_gemm_in(
    const float* __restrict__ x, const float* __restrict__ w_in,
    const float* __restrict__ b_in, unsigned short* __restrict__ xp)
{
    __shared__ short As[128 * AK];
    __shared__ short Ws[64 * AK];

    const int m0  = blockIdx.x * 128;
    const int co0 = blockIdx.y * 64;
    const int tid = threadIdx.x;
    const int n   = m0 >> 12;
    const int hw0 = m0 & 4095;

    const int wave = tid >> 6;
    const int lane = tid & 63;
    const int r16  = lane & 15;
    const int quad = lane >> 4;
    const int mw   = wave * 32;

    const float* xa = x + (size_t)n * CCH * HWSZ + hw0;

    f32x4 acc[2][4];
#pragma unroll
    for (int i = 0; i < 2; i++)
#pragma unroll
        for (int j = 0; j < 4; j++) acc[i][j] = (f32x4){0.f, 0.f, 0.f, 0.f};

    float apre[16];
    float wpre[8];

    // prefetch k0 = 0
#pragma unroll
    for (int l = 0; l < 8; l++) {
        int idx = tid + l * 256;
        int m = idx & 127, kp = idx >> 7;    // kp 0..15
        apre[2 * l + 0] = xa[(size_t)(2 * kp) * HWSZ + m];
        apre[2 * l + 1] = xa[(size_t)(2 * kp + 1) * HWSZ + m];
    }
#pragma unroll
    for (int l = 0; l < 4; l++) {
        int idx = tid + l * 256;
        int nn = idx & 63, kp = idx >> 6;    // 0..15
        wpre[2 * l + 0] = w_in[(size_t)(2 * kp) * CCH + co0 + nn];
        wpre[2 * l + 1] = w_in[(size_t)(2 * kp + 1) * CCH + co0 + nn];
    }

    for (int k0 = 0; k0 < CCH; k0 += 32) {
        // store prefetched tile into LDS
#pragma unroll
        for (int l = 0; l < 8; l++) {
            int idx = tid + l * 256;
            int m = idx & 127, kp = idx >> 7;
            ((unsigned int*)As)[(m * AK) / 2 + kp] = f2bf_pk(apre[2 * l], apre[2 * l + 1]);
        }
#pragma unroll
        for (int l = 0; l < 4; l++) {
            int idx = tid + l * 256;
            int nn = idx & 63, kp = idx >> 6;
            ((unsigned int*)Ws)[(nn * AK) / 2 + kp] = f2bf_pk(wpre[2 * l], wpre[2 * l + 1]);
        }
        __syncthreads();

        // issue next tile's global loads (overlap with MFMA below)
        if (k0 + 32 < CCH) {
            int k1 = k0 + 32;
#pragma unroll
            for (int l = 0; l < 8; l++) {
                int idx = tid + l * 256;
                int m = idx & 127, kp = idx >> 7;
                apre[2 * l + 0] = xa[(size_t)(k1 + 2 * kp) * HWSZ + m];
                apre[2 * l + 1] = xa[(size_t)(k1 + 2 * kp + 1) * HWSZ + m];
            }
#pragma unroll
            for (int l = 0; l < 4; l++) {
                int idx = tid + l * 256;
                int nn = idx & 63, kp = idx >> 6;
                wpre[2 * l + 0] = w_in[(size_t)(k1 + 2 * kp) * CCH + co0 + nn];
                wpre[2 * l + 1] = w_in[(size_t)(k1 + 2 * kp + 1) * CCH + co0 + nn];
            }
        }

        bf16x8 a0 = *(const bf16x8*)&As[(mw + r16) * AK + quad * 8];
        bf16x8 a1 = *(const bf16x8*)&As[(mw + 16 + r16) * AK + quad * 8];
#pragma unroll
        for (int nt = 0; nt < 4; nt++) {
            bf16x8 bfr = *(const bf16x8*)&Ws[(nt * 16 + r16) * AK + quad * 8];
            acc[0][nt] = __builtin_amdgcn_mfma_f32_16x16x32_bf16(a0, bfr, acc[0][nt], 0, 0, 0);
            acc[1][nt] = __builtin_amdgcn_mfma_f32_16x16x32_bf16(a1, bfr, acc[1][nt], 0, 0, 0);
        }
        __syncthreads();
    }

#pragma unroll
    for (int nt = 0; nt < 4; nt++) {
        int co = co0 + nt * 16 + r16;
        float bias = b_in[co];
#pragma unroll
        for (int mt = 0; mt < 2; mt++) {
            int mbase = mw + mt * 16 + quad * 4;
#pragma unroll
            for (int r = 0; r < 4; r++) {
                int hw = hw0 + mbase + r;
                int h = hw >> 6, w = hw & 63;
                xp[(((size_t)n * HIN + (h + 1)) * WIN + (w + 1)) * CCH + co] =
                    f2bf(acc[mt][nt][r] + bias);
            }
        }
    }
}

// ---------------------------------------------------------------------------
// Kernel 2: depthwise 3x3 + bias + LayerNorm(C) + exact GELU -> x1 (bf16)
// One block per (n,h): 512 threads = 8 waves; wave=channel, lane=w.
// ---------------------------------------------------------------------------
#define SDW_STRIDE 258
__global__ __launch_bounds__(512) void k_dw_ln_gelu(
    const float* __restrict__ x, const float* __restrict__ w_dw,
    const float* __restrict__ b_dw, const float* __restrict__ ln_g,
    const float* __restrict__ ln_b, unsigned short* __restrict__ x1)
{
    __shared__ unsigned short sdw[64 * SDW_STRIDE];   // [w][c] bf16
    __shared__ float r1s[8][64];
    __shared__ float r2s[8][64];
    __shared__ float mu_s[64];
    __shared__ float rs_s[64];

    const int h = blockIdx.x;
    const int n = blockIdx.y;
    const int tid = threadIdx.x;
    const int wave = tid >> 6;
    const int lane = tid & 63;        // = w in phase 1

    const float* xn = x + (size_t)n * CCH * HWSZ;
    const bool h0ok = (h > 0);
    const bool h2ok = (h < HH - 1);

    float s1 = 0.f, s2 = 0.f;

#pragma unroll 4
    for (int it = 0; it < 32; it++) {
        const int c = it * 8 + wave;
        const float* xc = xn + (size_t)c * HWSZ + h * WW + lane;
        float v0 = h0ok ? xc[-WW] : 0.f;
        float v1 = xc[0];
        float v2 = h2ok ? xc[WW] : 0.f;

        const float* wk = w_dw + c * 9;
        float acc = b_dw[c];

        float l0 = __shfl_up(v0, 1);  if (lane == 0)  l0 = 0.f;
        float r0 = __shfl_down(v0, 1); if (lane == 63) r0 = 0.f;
        acc += wk[0] * l0 + wk[1] * v0 + wk[2] * r0;

        float l1 = __shfl_up(v1, 1);  if (lane == 0)  l1 = 0.f;
        float r1 = __shfl_down(v1, 1); if (lane == 63) r1 = 0.f;
        acc += wk[3] * l1 + wk[4] * v1 + wk[5] * r1;

        float l2 = __shfl_up(v2, 1);  if (lane == 0)  l2 = 0.f;
        float r2 = __shfl_down(v2, 1); if (lane == 63) r2 = 0.f;
        acc += wk[6] * l2 + wk[7] * v2 + wk[8] * r2;

        s1 += acc;
        s2 += acc * acc;
        sdw[lane * SDW_STRIDE + c] = f2bf(acc);
    }

    r1s[wave][lane] = s1;
    r2s[wave][lane] = s2;
    __syncthreads();

    if (tid < 64) {
        float a1 = 0.f, a2 = 0.f;
#pragma unroll
        for (int q = 0; q < 8; q++) { a1 += r1s[q][tid]; a2 += r2s[q][tid]; }
        float mu = a1 * (1.0f / 256.0f);
        float var = a2 * (1.0f / 256.0f) - mu * mu;
        mu_s[tid] = mu;
        rs_s[tid] = rsqrtf(var + 1e-5f);
    }
    __syncthreads();

    const int c0 = (tid & 63) * 4;
    const int wq = tid >> 6;          // 0..7
    float g4[4], b4[4];
#pragma unroll
    for (int i = 0; i < 4; i++) { g4[i] = ln_g[c0 + i]; b4[i] = ln_b[c0 + i]; }

    unsigned short* x1p = x1 + (((size_t)n * HH + h) * WW) * CCH + c0;
#pragma unroll
    for (int pass = 0; pass < 8; pass++) {
        int w = wq + pass * 8;
        float mu = mu_s[w], rs = rs_s[w];
        const unsigned short* row = &sdw[w * SDW_STRIDE + c0];
        unsigned short tmp[4];
#pragma unroll
        for (int i = 0; i < 4; i++) {
            float v = (bf2f(row[i]) - mu) * rs * g4[i] + b4[i];
            tmp[i] = f2bf(0.5f * v * (1.0f + erff(v * 0.70710678118654752f)));
        }
        ushort4 o; o.x = tmp[0]; o.y = tmp[1]; o.z = tmp[2]; o.w = tmp[3];
        *(ushort4*)&x1p[(size_t)w * CCH] = o;
    }
}

// ---------------------------------------------------------------------------
// Kernel 3: x1(bf16) @ [w_off|w_mask] + bias -> off, msk (fp32)
// register-prefetch double buffer
// ---------------------------------------------------------------------------
__global__ __launch_bounds__(256) void k_gemm_offmask(
    const unsigned short* __restrict__ x1, const float* __restrict__ w_off,
    const float* __restrict__ b_off, const float* __restrict__ w_mask,
    const float* __restrict__ b_mask, float* __restrict__ off,
    float* __restrict__ msk)
{
    __shared__ short As[128 * AK];
    __shared__ short Ws[64 * AK];

    const int m0  = blockIdx.x * 128;
    const int co0 = blockIdx.y * 64;       // cols 0..215 valid
    const int tid = threadIdx.x;

    const int wave = tid >> 6;
    const int lane = tid & 63;
    const int r16  = lane & 15;
    const int quad = lane >> 4;
    const int mw   = wave * 32;

    const int am = tid >> 2, akq = tid & 3;         // A-staging coords
    const int wn = tid & 63, wkp = tid >> 6;        // W-staging coords (kp 0..3 per l)

    f32x4 acc[2][4];
#pragma unroll
    for (int i = 0; i < 2; i++)
#pragma unroll
        for (int j = 0; j < 4; j++) acc[i][j] = (f32x4){0.f, 0.f, 0.f, 0.f};

    uint4 apre[2];
    float wpre[8];

#pragma unroll
    for (int l = 0; l < 2; l++) {
        int m = am + l * 64;
        apre[l] = *(const uint4*)&x1[(size_t)(m0 + m) * CCH + akq * 8];
    }
#pragma unroll
    for (int l = 0; l < 4; l++) {
        int kp = wkp + l * 4;                // 0..15
        int col = co0 + wn;
        float v0 = 0.f, v1 = 0.f;
        if (col < 144) {
            v0 = w_off[(size_t)(2 * kp) * 144 + col];
            v1 = w_off[(size_t)(2 * kp + 1) * 144 + col];
        } else if (col < 216) {
            v0 = w_mask[(size_t)(2 * kp) * 72 + col - 144];
            v1 = w_mask[(size_t)(2 * kp + 1) * 72 + col - 144];
        }
        wpre[2 * l] = v0; wpre[2 * l + 1] = v1;
    }

    for (int k0 = 0; k0 < CCH; k0 += 32) {
#pragma unroll
        for (int l = 0; l < 2; l++) {
            int m = am + l * 64;
            *(uint4*)&As[m * AK + akq * 8] = apre[l];
        }
#pragma unroll
        for (int l = 0; l < 4; l++) {
            int kp = wkp + l * 4;
            ((unsigned int*)Ws)[(wn * AK) / 2 + kp] = f2bf_pk(wpre[2 * l], wpre[2 * l + 1]);
        }
        __syncthreads();

        if (k0 + 32 < CCH) {
            int k1 = k0 + 32;
#pragma unroll
            for (int l = 0; l < 2; l++) {
                int m = am + l * 64;
                apre[l] = *(const uint4*)&x1[(size_t)(m0 + m) * CCH + k1 + akq * 8];
            }
#pragma unroll
            for (int l = 0; l < 4; l++) {
                int kp = wkp + l * 4;
                int col = co0 + wn;
                float v0 = 0.f, v1 = 0.f;
                if (col < 144) {
                    v0 = w_off[(size_t)(k1 + 2 * kp) * 144 + col];
                    v1 = w_off[(size_t)(k1 + 2 * kp + 1) * 144 + col];
                } else if (col < 216) {
                    v0 = w_mask[(size_t)(k1 + 2 * kp) * 72 + col - 144];
                    v1 = w_mask[(size_t)(k1 + 2 * kp + 1) * 72 + col - 144];
                }
                wpre[2 * l] = v0; wpre[2 * l + 1] = v1;
            }
        }

        bf16x8 a0 = *(const bf16x8*)&As[(mw + r16) * AK + quad * 8];
        bf16x8 a1 = *(const bf16x8*)&As[(mw + 16 + r16) * AK + quad * 8];
#pragma unroll
        for (int nt = 0; nt < 4; nt++) {
            bf16x8 bfr = *(const bf16x8*)&Ws[(nt * 16 + r16) * AK + quad * 8];
            acc[0][nt] = __builtin_amdgcn_mfma_f32_16x16x32_bf16(a0, bfr, acc[0][nt], 0, 0, 0);
            acc[1][nt] = __builtin_amdgcn_mfma_f32_16x16x32_bf16(a1, bfr, acc[1][nt], 0, 0, 0);
        }
        __syncthreads();
    }

#pragma unroll
    for (int nt = 0; nt < 4; nt++) {
        int col = co0 + nt * 16 + r16;
        if (col >= 216) continue;
        float bias = (col < 144) ? b_off[col] : b_mask[col - 144];
#pragma unroll
        for (int mt = 0; mt < 2; mt++) {
            int mbase = m0 + mw + mt * 16 + quad * 4;
#pragma unroll
            for (int r = 0; r < 4; r++) {
                int p = mbase + r;
                float v = acc[mt][nt][r] + bias;
                if (col < 144) off[(size_t)p * 144 + col] = v;
                else           msk[(size_t)p * 72 + col - 144] = v;
            }
        }
    }
}

// ---------------------------------------------------------------------------
// Kernel 4: deformable sampling + aggregation, 8 px/block, 8 ch/lane (uint4)
// ---------------------------------------------------------------------------
__device__ __forceinline__ void acc8_tap(float* a, uint4 vv, float wgt) {
    a[0] += wgt * __uint_as_float(vv.x << 16);
    a[1] += wgt * __uint_as_float(vv.x & 0xffff0000u);
    a[2] += wgt * __uint_as_float(vv.y << 16);
    a[3] += wgt * __uint_as_float(vv.y & 0xffff0000u);
    a[4] += wgt * __uint_as_float(vv.z << 16);
    a[5] += wgt * __uint_as_float(vv.z & 0xffff0000u);
    a[6] += wgt * __uint_as_float(vv.w << 16);
    a[7] += wgt * __uint_as_float(vv.w & 0xffff0000u);
}

__global__ __launch_bounds__(256) void k_sample_agg(
    const unsigned short* __restrict__ xp, const float* __restrict__ off,
    const float* __restrict__ msk, unsigned short* __restrict__ agg)
{
    __shared__ float  sm[576];
    __shared__ int2   tco[576];
    __shared__ float4 twt[576];

    const int tid = threadIdx.x;
    const int s0 = blockIdx.x * 8;

    if (tid < 64) {
        const int pix = tid >> 3, g = tid & 7;
        const float* mskp = msk + (size_t)(s0 + pix) * 72 + g * 9;
        float e[9];
        float mx = -1e30f;
#pragma unroll
        for (int p = 0; p < PP; p++) { e[p] = mskp[p]; mx = fmaxf(mx, e[p]); }
        float sum = 0.f;
#pragma unroll
        for (int p = 0; p < PP; p++) { e[p] = __expf(e[p] - mx); sum += e[p]; }
        float rs = 1.0f / sum;
#pragma unroll
        for (int p = 0; p < PP; p++) sm[tid * 9 + p] = e[p] * rs;
    }
    __syncthreads();

    for (int idx = tid; idx < 576; idx += 256) {
        int pix = idx / 72;
        int rem = idx - pix * 72;
        int g = rem / 9;
        int p = rem - g * 9;
        int s = s0 + pix;
        int hw = s & 4095;
        int h = hw >> 6, w = hw & 63;
        const float* offp = off + (size_t)s * 144 + g * 18 + p * 2;
        float ox = offp[0], oy = offp[1];
        int i = p / 3, j = p - i * 3;
        float fx = (float)(w + i) + ox;
        float fy = (float)(h + j) + oy;
        float x0f = floorf(fx), y0f = floorf(fy);
        int x0 = (int)x0f, y0 = (int)y0f;
        float wx = fx - x0f, wy = fy - y0f;
        float m = sm[idx];
        float w00 = (1.f - wx) * (1.f - wy) * m;
        float w10 = wx * (1.f - wy) * m;
        float w01 = (1.f - wx) * wy * m;
        float w11 = wx * wy * m;
        int x1c = x0 + 1, y1c = y0 + 1;
        if (!((x0  >= 0) && (x0  < WIN))) { w00 = 0.f; w01 = 0.f; }
        if (!((x1c >= 0) && (x1c < WIN))) { w10 = 0.f; w11 = 0.f; }
        if (!((y0  >= 0) && (y0  < HIN))) { w00 = 0.f; w10 = 0.f; }
        if (!((y1c >= 0) && (y1c < HIN))) { w01 = 0.f; w11 = 0.f; }
        int cx0 = min(max(x0, 0), WIN - 1), cx1 = min(max(x1c, 0), WIN - 1);
        int cy0 = min(max(y0, 0), HIN - 1), cy1 = min(max(y1c, 0), HIN - 1);
        tco[idx] = make_int2(cx0 | (cx1 << 16), cy0 | (cy1 << 16));
        twt[idx] = make_float4(w00, w10, w01, w11);
    }
    __syncthreads();

    const int pix = tid >> 5;
    const int l5 = tid & 31;
    const int g = l5 >> 2, c8 = l5 & 3;
    const int s = s0 + pix;
    const int n = s >> 12;
    const unsigned short* base = xp + (size_t)n * HIN * WIN * CCH + g * GCH + c8 * 8;
    const int tbase = pix * 72 + g * 9;

    float a[8];
#pragma unroll
    for (int i = 0; i < 8; i++) a[i] = 0.f;

#pragma unroll
    for (int p = 0; p < PP; p++) {
        int2 cc = tco[tbase + p];
        float4 wt = twt[tbase + p];
        int cx0 = cc.x & 0xFFFF, cx1 = cc.x >> 16;
        int cy0 = cc.y & 0xFFFF, cy1 = cc.y >> 16;
        const unsigned short* r0 = base + (size_t)(cy0 * WIN) * CCH;
        const unsigned short* r1 = base + (size_t)(cy1 * WIN) * CCH;
        uint4 v00 = *(const uint4*)&r0[(size_t)cx0 * CCH];
        uint4 v10 = *(const uint4*)&r0[(size_t)cx1 * CCH];
        uint4 v01 = *(const uint4*)&r1[(size_t)cx0 * CCH];
        uint4 v11 = *(const uint4*)&r1[(size_t)cx1 * CCH];
        acc8_tap(a, v00, wt.x);
        acc8_tap(a, v10, wt.y);
        acc8_tap(a, v01, wt.z);
        acc8_tap(a, v11, wt.w);
    }

    uint4 o;
    o.x = (unsigned int)f2bf(a[0]) | ((unsigned int)f2bf(a[1]) << 16);
    o.y = (unsigned int)f2bf(a[2]) | ((unsigned int)f2bf(a[3]) << 16);
    o.z = (unsigned int)f2bf(a[4]) | ((unsigned int)f2bf(a[5]) << 16);
    o.w = (unsigned int)f2bf(a[6]) | ((unsigned int)f2bf(a[7]) << 16);
    *(uint4*)&agg[(size_t)s * CCH + g * GCH + c8 * 8] = o;
}

// ---------------------------------------------------------------------------
// Kernel 5: agg(bf16) @ w_out + b_out -> BN -> SiLU -> out (NCHW fp32)
// register-prefetch double buffer
// ---------------------------------------------------------------------------
__global__ __launch_bounds__(256) void k_gemm_out(
    const unsigned short* __restrict__ agg, const float* __restrict__ w_out,
    const float* __restrict__ b_out, const float* __restrict__ bn_g,
    const float* __restrict__ bn_b, const float* __restrict__ bn_mean,
    const float* __restrict__ bn_var, float* __restrict__ out)
{
    __shared__ short As[128 * AK];
    __shared__ short Ws[64 * AK];

    const int m0  = blockIdx.x * 128;
    const int co0 = blockIdx.y * 64;
    const int tid = threadIdx.x;
    const int n   = m0 >> 12;
    const int hw0 = m0 & 4095;

    const int wave = tid >> 6;
    const int lane = tid & 63;
    const int r16  = lane & 15;
    const int quad = lane >> 4;
    const int mw   = wave * 32;

    const int am = tid >> 2, akq = tid & 3;
    const int wn = tid & 63, wkp = tid >> 6;

    f32x4 acc[2][4];
#pragma unroll
    for (int i = 0; i < 2; i++)
#pragma unroll
        for (int j = 0; j < 4; j++) acc[i][j] = (f32x4){0.f, 0.f, 0.f, 0.f};

    uint4 apre[2];
    float wpre[8];

#pragma unroll
    for (int l = 0; l < 2; l++) {
        int m = am + l * 64;
        apre[l] = *(const uint4*)&agg[(size_t)(m0 + m) * CCH + akq * 8];
    }
#pragma unroll
    for (int l = 0; l < 4; l++) {
        int kp = wkp + l * 4;
        wpre[2 * l + 0] = w_out[(size_t)(2 * kp) * CCH + co0 + wn];
        wpre[2 * l + 1] = w_out[(size_t)(2 * kp + 1) * CCH + co0 + wn];
    }

    for (int k0 = 0; k0 < CCH; k0 += 32) {
#pragma unroll
        for (int l = 0; l < 2; l++) {
            int m = am + l * 64;
            *(uint4*)&As[m * AK + akq * 8] = apre[l];
        }
#pragma unroll
        for (int l = 0; l < 4; l++) {
            int kp = wkp + l * 4;
            ((unsigned int*)Ws)[(wn * AK) / 2 + kp] = f2bf_pk(wpre[2 * l], wpre[2 * l + 1]);
        }
        __syncthreads();

        if (k0 + 32 < CCH) {
            int k1 = k0 + 32;
#pragma unroll
            for (int l = 0; l < 2; l++) {
                int m = am + l * 64;
                apre[l] = *(const uint4*)&agg[(size_t)(m0 + m) * CCH + k1 + akq * 8];
            }
#pragma unroll
            for (int l = 0; l < 4; l++) {
                int kp = wkp + l * 4;
                wpre[2 * l + 0] = w_out[(size_t)(k1 + 2 * kp) * CCH + co0 + wn];
                wpre[2 * l + 1] = w_out[(size_t)(k1 + 2 * kp + 1) * CCH + co0 + wn];
            }
        }

        bf16x8 a0 = *(const bf16x8*)&As[(mw + r16) * AK + quad * 8];
        bf16x8 a1 = *(const bf16x8*)&As[(mw + 16 + r16) * AK + quad * 8];
#pragma unroll
        for (int nt = 0; nt < 4; nt++) {
            bf16x8 bfr = *(const bf16x8*)&Ws[(nt * 16 + r16) * AK + quad * 8];
            acc[0][nt] = __builtin_amdgcn_mfma_f32_16x16x32_bf16(a0, bfr, acc[0][nt], 0, 0, 0);
            acc[1][nt] = __builtin_amdgcn_mfma_f32_16x16x32_bf16(a1, bfr, acc[1][nt], 0, 0, 0);
        }
        __syncthreads();
    }

#pragma unroll
    for (int nt = 0; nt < 4; nt++) {
        int co = co0 + nt * 16 + r16;
        float mean = bn_mean[co];
        float rstd = rsqrtf(bn_var[co] + 1e-5f);
        float gg = bn_g[co], bb = bn_b[co], bo = b_out[co];
#pragma unroll
        for (int mt = 0; mt < 2; mt++) {
            int hwb = hw0 + mw + mt * 16 + quad * 4;
            float tmp[4];
#pragma unroll
            for (int r = 0; r < 4; r++) {
                float y = acc[mt][nt][r] + bo;
                float yh = (y - mean) * rstd * gg + bb;
                tmp[r] = yh / (1.0f + __expf(-yh));
            }
            float4 v = make_float4(tmp[0], tmp[1], tmp[2], tmp[3]);
            *(float4*)&out[((size_t)n * CCH + co) * HWSZ + hwb] = v;
        }
    }
}

// ---------------------------------------------------------------------------
extern "C" void kernel_launch(void* const* d_in, const int* in_sizes, int n_in,
                              void* d_out, int out_size, void* d_ws, size_t ws_size,
                              hipStream_t stream)
{
    const float* x       = (const float*)d_in[0];
    const float* w_in    = (const float*)d_in[1];
    const float* b_in    = (const float*)d_in[2];
    const float* w_dw    = (const float*)d_in[3];
    const float* b_dw    = (const float*)d_in[4];
    const float* ln_g    = (const float*)d_in[5];
    const float* ln_b    = (const float*)d_in[6];
    const float* w_off   = (const float*)d_in[7];
    const float* b_off   = (const float*)d_in[8];
    const float* w_mask  = (const float*)d_in[9];
    const float* b_mask  = (const float*)d_in[10];
    const float* w_out   = (const float*)d_in[11];
    const float* b_out   = (const float*)d_in[12];
    const float* bn_g    = (const float*)d_in[13];
    const float* bn_b    = (const float*)d_in[14];
    const float* bn_mean = (const float*)d_in[15];
    const float* bn_var  = (const float*)d_in[16];
    float* out = (float*)d_out;

    unsigned short* xp  = (unsigned short*)d_ws;
    unsigned short* x1  = xp + XP_ELEMS;
    unsigned short* agg = x1 + X1_ELEMS;
    float* off = (float*)(agg + AGG_ELEMS);
    float* msk = off + OFF_ELEMS;

    k_zero_ring<<<dim3(1040), 64, 0, stream>>>(xp);
    k_gemm_in<<<dim3(128, 4), 256, 0, stream>>>(x, w_in, b_in, xp);
    k_dw_ln_gelu<<<dim3(64, 4), 512, 0, stream>>>(x, w_dw, b_dw, ln_g, ln_b, x1);
    k_gemm_offmask<<<dim3(128, 4), 256, 0, stream>>>(x1, w_off, b_off, w_mask, b_mask, off, msk);
    k_sample_agg<<<dim3(2048), 256, 0, stream>>>(xp, off, msk, agg);
    k_gemm_out<<<dim3(128, 4), 256, 0, stream>>>(agg, w_out, b_out, bn_g, bn_b, bn_mean, bn_var, out);
}